// Round 5
// baseline (980.568 us; speedup 1.0000x reference)
//
#include <hip/hip_runtime.h>

// AttentionBlock — x(8,1024,4,256) fp32, full 4096x4096 attention per batch
// (heads merged), qkv interleaved (e = 3*dd + which), MLP 256->1024->256.
// R5: k_attn — R=2 q-tiles per wave (64 q), split-K over keys (exact with
// no-max softmax), all staging via global_load_lds with source-swizzled
// conflict-free LDS layouts, partial O/l merged by k_merge.
// ws layout (131 MB):
//   0        : w_qkv bf16 de-interleaved [Wq|Wk|Wv] (scale folded into Wq)
//   512K     : w1 bf16 (1024x256)
//   1M       : w2 bf16 (256x1024)
//   2M..18M  : XN bf16 (32768x256)
//   18M..34M : Q bf16 [b][i][d]  (pre-scaled by 0.0625*log2e via Wq)
//   34M..50M : K bf16 [b][i][d]
//   50M..66M : V^T bf16 [b][d][i]
//   66M..130M: Opart fp32 [split][b][q][d]
//   130M+    : lpart fp32 [split][b*4096+q]

typedef __attribute__((ext_vector_type(8))) short bf16x8;
typedef __attribute__((ext_vector_type(4))) short bf16x4;
typedef __attribute__((ext_vector_type(4))) float f32x4;
typedef __attribute__((ext_vector_type(16))) float f32x16;

static __device__ __forceinline__ short f2bf(float f) {
    union { float f; unsigned u; } v; v.f = f;
    unsigned r = (v.u + 0x7FFFu + ((v.u >> 16) & 1u)) >> 16;
    return (short)r;
}

static __device__ __forceinline__ void gll16(const void* g, void* l) {
    __builtin_amdgcn_global_load_lds(
        (const __attribute__((address_space(1))) unsigned*)g,
        (__attribute__((address_space(3))) unsigned*)l, 16, 0, 0);
}

// ---------------- weights fp32 -> bf16, de-interleave w_qkv ----------------
__global__ __launch_bounds__(256) void k_cvt(const float* __restrict__ wqkv,
                                             const float* __restrict__ w1,
                                             const float* __restrict__ w2,
                                             short* __restrict__ owqkv,
                                             short* __restrict__ ow1,
                                             short* __restrict__ ow2) {
    int i = blockIdx.x * 256 + threadIdx.x;
    if (i < 196608) {
        int e = i >> 8, col = i & 255;
        int dd = e / 3, which = e - dd * 3;
        float v = wqkv[i];
        if (which == 0) v *= 0.0625f * 1.44269504f;   // fold scale*log2e into Wq
        owqkv[((which << 8) + dd) * 256 + col] = f2bf(v);
    }
    if (i < 262144) { ow1[i] = f2bf(w1[i]); ow2[i] = f2bf(w2[i]); }
}

// ---------------- layernorm: one wave per row of 256 ----------------
__global__ __launch_bounds__(256) void k_ln(const float* __restrict__ x,
                                            const float* __restrict__ g,
                                            const float* __restrict__ bta,
                                            short* __restrict__ out) {
    int w = threadIdx.x >> 6, lane = threadIdx.x & 63;
    long row = (long)blockIdx.x * 4 + w;
    float4 v = *((const float4*)(x + row * 256) + lane);
    float s = v.x + v.y + v.z + v.w;
    float q = v.x * v.x + v.y * v.y + v.z * v.z + v.w * v.w;
    for (int off = 1; off < 64; off <<= 1) {
        s += __shfl_xor(s, off);
        q += __shfl_xor(q, off);
    }
    float mean = s * (1.0f / 256.0f);
    float var = q * (1.0f / 256.0f) - mean * mean;
    float rstd = rsqrtf(var + 1e-5f);
    float4 gg = *((const float4*)g + lane);
    float4 bb = *((const float4*)bta + lane);
    short4 o;
    o.x = f2bf((v.x - mean) * rstd * gg.x + bb.x);
    o.y = f2bf((v.y - mean) * rstd * gg.y + bb.y);
    o.z = f2bf((v.z - mean) * rstd * gg.z + bb.z);
    o.w = f2bf((v.w - mean) * rstd * gg.w + bb.w);
    *((short4*)(out + row * 256) + lane) = o;
}

// ---------------- QKV projection GEMM + split scatter ----------------
__global__ __launch_bounds__(256) void k_qkv(const short* __restrict__ xn,
                                             const short* __restrict__ wb,
                                             short* __restrict__ Q,
                                             short* __restrict__ K,
                                             short* __restrict__ VT) {
    __shared__ __attribute__((aligned(16))) short lds_a[64 * 264];
    __shared__ __attribute__((aligned(16))) short lds_b[64 * 264];
    int t = threadIdx.x;
    int m0 = blockIdx.y * 64, n0 = blockIdx.x * 64;
    const int4* ga = (const int4*)xn;
    const int4* gb = (const int4*)wb;
    int4* la = (int4*)lds_a;
    int4* lb = (int4*)lds_b;
    for (int it = 0; it < 8; it++) {
        int c = t + 256 * it;
        int r = c >> 5, k = c & 31;
        la[r * 33 + k] = ga[(long)(m0 + r) * 32 + k];
        lb[r * 33 + k] = gb[(n0 + r) * 32 + k];
    }
    __syncthreads();
    int w = t >> 6, lane = t & 63, ln = lane & 15, qd = lane >> 4;
    int moff = (w >> 1) * 32, noff = (w & 1) * 32;
    f32x4 acc[2][2] = {};
    for (int ks = 0; ks < 8; ks++) {
        bf16x8 a0 = *(const bf16x8*)&lds_a[(moff + ln) * 264 + ks * 32 + qd * 8];
        bf16x8 a1 = *(const bf16x8*)&lds_a[(moff + 16 + ln) * 264 + ks * 32 + qd * 8];
        bf16x8 b0 = *(const bf16x8*)&lds_b[(noff + ln) * 264 + ks * 32 + qd * 8];
        bf16x8 b1 = *(const bf16x8*)&lds_b[(noff + 16 + ln) * 264 + ks * 32 + qd * 8];
        acc[0][0] = __builtin_amdgcn_mfma_f32_16x16x32_bf16(a0, b0, acc[0][0], 0, 0, 0);
        acc[0][1] = __builtin_amdgcn_mfma_f32_16x16x32_bf16(a0, b1, acc[0][1], 0, 0, 0);
        acc[1][0] = __builtin_amdgcn_mfma_f32_16x16x32_bf16(a1, b0, acc[1][0], 0, 0, 0);
        acc[1][1] = __builtin_amdgcn_mfma_f32_16x16x32_bf16(a1, b1, acc[1][1], 0, 0, 0);
    }
    for (int mi = 0; mi < 2; mi++)
        for (int nj = 0; nj < 2; nj++)
            for (int rg = 0; rg < 4; rg++) {
                float v = acc[mi][nj][rg];
                int gr = m0 + moff + mi * 16 + qd * 4 + rg;
                int e = n0 + noff + nj * 16 + ln;
                int which = e >> 8, dd = e & 255;
                short bv = f2bf(v);
                if (which == 0) Q[(long)gr * 256 + dd] = bv;
                else if (which == 1) K[(long)gr * 256 + dd] = bv;
                else {
                    int b = gr >> 12, i = gr & 4095;
                    VT[((long)b * 256 + dd) * 4096 + i] = bv;
                }
            }
}

// ---------------- flash attention v5 (split-K, R=2 q-tiles/wave) ------------
// grid (32, 8): x = qt*2 + split. 4 waves x 64 q = 256 q/block, 2048 keys/block
// in 64 iters of 32. All staging via DMA with source-swizzled layouts.
__global__ __launch_bounds__(256, 1) void k_attn(const short* __restrict__ Q,
                                                 const short* __restrict__ K,
                                                 const short* __restrict__ VT,
                                                 float* __restrict__ Opart,
                                                 float* __restrict__ lpart) {
    __shared__ __attribute__((aligned(16))) short lds_k[2][32 * 256];  // 16 KB x2
    __shared__ __attribute__((aligned(16))) short lds_v[2][256 * 64 / 2];  // 16 KB x2
    int t = threadIdx.x, w = t >> 6, l = t & 63, l5 = l & 31, h = l >> 5;
    int qt = blockIdx.x >> 1, sp = blockIdx.x & 1;
    int b = blockIdx.y;
    int q0 = qt * 256 + w * 32;     // r=0 tile; r=1 tile at q0+128

    // Q fragments: B-operand of 32x32x16 (n=q=lane&31, k=(lane>>5)*8+j)
    bf16x8 qf[2][16];
    #pragma unroll
    for (int r = 0; r < 2; r++) {
        const short* qrow = Q + ((long)(b * 4096 + q0 + r * 128 + l5)) * 256;
        #pragma unroll
        for (int kc = 0; kc < 16; kc++)
            qf[r][kc] = *(const bf16x8*)(qrow + kc * 16 + h * 8);
    }
    f32x16 O[2][8] = {};
    float ls0 = 0.f, ls1 = 0.f;

    const char* Kb = (const char*)K + ((long)(b * 4096 + sp * 2048)) * 512;
    const char* Vb = (const char*)VT + (long)b * 256 * 8192 + (long)sp * 4096;

    // K DMA: wave w rows w*8..w*8+7; LDS slot l5 of row r holds chunk l5^r.
    int koff[4];
    #pragma unroll
    for (int i = 0; i < 4; i++) {
        int r = w * 8 + i * 2 + h;
        koff[i] = r * 512 + ((l5 ^ r) * 16);
    }
    // V DMA: linear slot s = w*256 + i*64 + l; d = s>>2; holds chunk
    // k4 = (s&3) ^ ((d>>1)&3)  (16B = 8 keys... 16B = k4-th 8-key group? 16B = 8 bf16 = 8 keys)
    int voff[4];
    #pragma unroll
    for (int i = 0; i < 4; i++) {
        int s = w * 256 + i * 64 + l;
        int d = s >> 2;
        int k4 = (s & 3) ^ ((d >> 1) & 3);
        voff[i] = d * 8192 + k4 * 16;
    }
    int xl = (l5 >> 1) & 3;   // V read swizzle term, dt-invariant

    // stage tile 0
    #pragma unroll
    for (int i = 0; i < 4; i++)
        gll16(Kb + koff[i], (char*)lds_k[0] + (w * 8 + i * 2) * 512);
    #pragma unroll
    for (int i = 0; i < 4; i++)
        gll16(Vb + voff[i], (char*)lds_v[0] + (w * 256 + i * 64) * 16);
    __syncthreads();

    for (int jt = 0; jt < 64; jt++) {
        int cur = jt & 1;
        if (jt < 63) {
            long ka = (long)(jt + 1) * 16384;    // 32 rows * 512 B
            long va = (long)(jt + 1) * 64;       // 32 keys * 2 B
            #pragma unroll
            for (int i = 0; i < 4; i++)
                gll16(Kb + ka + koff[i], (char*)lds_k[cur ^ 1] + (w * 8 + i * 2) * 512);
            #pragma unroll
            for (int i = 0; i < 4; i++)
                gll16(Vb + va + voff[i], (char*)lds_v[cur ^ 1] + (w * 256 + i * 64) * 16);
        }
        const short* lk = lds_k[cur];
        const char* lv = (const char*)lds_v[cur];
        // S^T[key][q] = sum_d K[key][d] * Q[q][d] — K frag shared by both r
        f32x16 st0 = {}, st1 = {};
        #pragma unroll
        for (int kc = 0; kc < 16; kc++) {
            int cc = kc * 2 + h;
            bf16x8 a = *(const bf16x8*)(lk + (l5 * 32 + (cc ^ l5)) * 8);
            st0 = __builtin_amdgcn_mfma_f32_32x32x16_bf16(a, qf[0][kc], st0, 0, 0, 0);
            st1 = __builtin_amdgcn_mfma_f32_32x32x16_bf16(a, qf[1][kc], st1, 0, 0, 0);
        }
        // P = exp2(S^T); reg quad r4 == B-frag (k chunk) of 32x32x8
        bf16x4 pf0[4], pf1[4];
        #pragma unroll
        for (int r4 = 0; r4 < 4; r4++) {
            float a0 = __builtin_amdgcn_exp2f(st0[r4 * 4 + 0]);
            float a1 = __builtin_amdgcn_exp2f(st0[r4 * 4 + 1]);
            float a2 = __builtin_amdgcn_exp2f(st0[r4 * 4 + 2]);
            float a3 = __builtin_amdgcn_exp2f(st0[r4 * 4 + 3]);
            ls0 += (a0 + a1) + (a2 + a3);
            union { float f; unsigned u; } x0, x1, x2, x3;
            x0.f = a0; x1.f = a1; x2.f = a2; x3.f = a3;
            union { unsigned u[2]; bf16x4 v; } pk;
            pk.u[0] = __builtin_amdgcn_perm(x1.u + 0x8000u, x0.u + 0x8000u, 0x07060302u);
            pk.u[1] = __builtin_amdgcn_perm(x3.u + 0x8000u, x2.u + 0x8000u, 0x07060302u);
            pf0[r4] = pk.v;
            float b0 = __builtin_amdgcn_exp2f(st1[r4 * 4 + 0]);
            float b1 = __builtin_amdgcn_exp2f(st1[r4 * 4 + 1]);
            float b2 = __builtin_amdgcn_exp2f(st1[r4 * 4 + 2]);
            float b3 = __builtin_amdgcn_exp2f(st1[r4 * 4 + 3]);
            ls1 += (b0 + b1) + (b2 + b3);
            x0.f = b0; x1.f = b1; x2.f = b2; x3.f = b3;
            pk.u[0] = __builtin_amdgcn_perm(x1.u + 0x8000u, x0.u + 0x8000u, 0x07060302u);
            pk.u[1] = __builtin_amdgcn_perm(x3.u + 0x8000u, x2.u + 0x8000u, 0x07060302u);
            pf1[r4] = pk.v;
        }
        // O^T[d][q] += V^T[d][key] P^T[key][q] — V frag shared by both r
        #pragma unroll
        for (int dt = 0; dt < 8; dt++) {
            int d = dt * 32 + l5;
            const char* vrow = lv + d * 64;
            #pragma unroll
            for (int k4 = 0; k4 < 4; k4++) {
                bf16x4 va = *(const bf16x4*)(vrow + ((k4 ^ xl) * 16 + h * 8));
                O[0][dt] = __builtin_amdgcn_mfma_f32_32x32x8bf16_1k(va, pf0[k4], O[0][dt], 0, 0, 0);
                O[1][dt] = __builtin_amdgcn_mfma_f32_32x32x8bf16_1k(va, pf1[k4], O[1][dt], 0, 0, 0);
            }
        }
        __syncthreads();
    }

    // epilogue: write partial l and partial O (no divide; merge kernel does it)
    long obase = ((long)(sp * 8 + b)) * 4096 * 256;
    long lbase = (long)(sp * 8 + b) * 4096;
    float* fscr = (float*)lds_k[0] + w * (32 * 33);
    #pragma unroll
    for (int r = 0; r < 2; r++) {
        float lsv = r ? ls1 : ls0;
        float lt = lsv + __shfl_xor(lsv, 32);
        int qb = q0 + r * 128;
        if (h == 0) lpart[lbase + qb + l5] = lt;
        #pragma unroll
        for (int dt = 0; dt < 8; dt++) {
            #pragma unroll
            for (int rg = 0; rg < 16; rg++) {
                int drow = (rg & 3) + 8 * (rg >> 2) + 4 * h;
                fscr[drow * 33 + l5] = O[r][dt][rg];
            }
            asm volatile("s_waitcnt lgkmcnt(0)" ::: "memory");
            #pragma unroll
            for (int it = 0; it < 16; it++) {
                int ql = it * 2 + h;
                float v = fscr[l5 * 33 + ql];
                Opart[obase + (long)(qb + ql) * 256 + dt * 32 + l5] = v;
            }
            asm volatile("s_waitcnt lgkmcnt(0)" ::: "memory");
        }
    }
}

// ---------------- merge: out = x + (Oa+Ob) / (la+lb) ----------------
__global__ __launch_bounds__(256) void k_merge(const float* __restrict__ x,
                                               const float* __restrict__ Op,
                                               const float* __restrict__ lp,
                                               float* __restrict__ out) {
    long i4 = (long)blockIdx.x * 256 + threadIdx.x;   // float4 units, 2097152 total
    long i = i4 * 4;
    int row = (int)(i >> 8);
    float li = lp[row] + lp[32768 + row];
    float rinv = 1.0f / li;
    float4 a = *(const float4*)(Op + i);
    float4 bq = *(const float4*)(Op + (long)8 * 4096 * 256 + i);
    float4 xx = *(const float4*)(x + i);
    float4 o;
    o.x = xx.x + (a.x + bq.x) * rinv;
    o.y = xx.y + (a.y + bq.y) * rinv;
    o.z = xx.z + (a.z + bq.z) * rinv;
    o.w = xx.w + (a.w + bq.w) * rinv;
    *(float4*)(out + i) = o;
}

// ---------------- fused MLP: out += silu(xn W1^T + b1) W2^T + b2 ------------
__global__ __launch_bounds__(256) void k_mlp(const short* __restrict__ xn,
                                             const short* __restrict__ w1b,
                                             const short* __restrict__ w2b,
                                             const float* __restrict__ b1,
                                             const float* __restrict__ b2,
                                             float* __restrict__ out) {
    __shared__ __attribute__((aligned(16))) short lds_w[2][16 * 256];  // 8 KB x2
    __shared__ __attribute__((aligned(16))) short lds_h[4][16 * 264];
    int t = threadIdx.x, w = t >> 6, l = t & 63, ln = l & 15, qd = l >> 4;
    int R0 = blockIdx.x * 64 + w * 16;
    short* lhs = lds_h[w];

    bf16x8 a1f[8];
    #pragma unroll
    for (int kc = 0; kc < 8; kc++)
        a1f[kc] = *(const bf16x8*)(xn + (long)(R0 + ln) * 256 + kc * 32 + qd * 8);

    long s1off[2], s2off[2]; int wlds[2];
    #pragma unroll
    for (int i = 0; i < 2; i++) {
        int r = w * 4 + i * 2 + (l >> 5);
        int ch = (l & 31) ^ r;
        s1off[i] = (long)r * 512 + ch * 16;
        s2off[i] = (long)r * 2048 + ch * 16;
        wlds[i] = (w * 4 + i * 2) * 512;
    }
    const char* W1c = (const char*)w1b;
    const char* W2c = (const char*)w2b;

    f32x4 Oc[16] = {};
    #pragma unroll
    for (int i = 0; i < 2; i++)
        gll16(W1c + s1off[i], (char*)lds_w[0] + wlds[i]);
    __syncthreads();
    int cur = 0;

    for (int pass = 0; pass < 4; pass++) {
        for (int nt = 0; nt < 16; nt++) {
            if (nt < 15) {
                long base = (long)(pass * 256 + (nt + 1) * 16) * 512;
                #pragma unroll
                for (int i = 0; i < 2; i++)
                    gll16(W1c + base + s1off[i], (char*)lds_w[cur ^ 1] + wlds[i]);
            } else {
                long base = (long)pass * 512;
                #pragma unroll
                for (int i = 0; i < 2; i++)
                    gll16(W2c + base + s2off[i], (char*)lds_w[cur ^ 1] + wlds[i]);
            }
            f32x4 acc = {};
            const short* lw = lds_w[cur];
            #pragma unroll
            for (int kc = 0; kc < 8; kc++) {
                int cc = kc * 4 + qd;
                bf16x8 bf = *(const bf16x8*)(lw + (ln * 32 + (cc ^ ln)) * 8);
                acc = __builtin_amdgcn_mfma_f32_16x16x32_bf16(a1f[kc], bf, acc, 0, 0, 0);
            }
            float bb = b1[pass * 256 + nt * 16 + ln];
            #pragma unroll
            for (int rg = 0; rg < 4; rg++) {
                float z = acc[rg] + bb;
                float sv = z / (1.0f + __expf(-z));
                lhs[(qd * 4 + rg) * 264 + nt * 16 + ln] = f2bf(sv);
            }
            __syncthreads();
            cur ^= 1;
        }
        bf16x8 a2f[8];
        #pragma unroll
        for (int kc = 0; kc < 8; kc++)
            a2f[kc] = *(const bf16x8*)&lhs[ln * 264 + kc * 32 + qd * 8];
        for (int nt = 0; nt < 16; nt++) {
            if (nt < 15) {
                long base = (long)((nt + 1) * 16) * 2048 + (long)pass * 512;
                #pragma unroll
                for (int i = 0; i < 2; i++)
                    gll16(W2c + base + s2off[i], (char*)lds_w[cur ^ 1] + wlds[i]);
            } else if (pass < 3) {
                long base = (long)((pass + 1) * 256) * 512;
                #pragma unroll
                for (int i = 0; i < 2; i++)
                    gll16(W1c + base + s1off[i], (char*)lds_w[cur ^ 1] + wlds[i]);
            }
            const short* lw = lds_w[cur];
            #pragma unroll
            for (int kc = 0; kc < 8; kc++) {
                int cc = kc * 4 + qd;
                bf16x8 bf = *(const bf16x8*)(lw + (ln * 32 + (cc ^ ln)) * 8);
                Oc[nt] = __builtin_amdgcn_mfma_f32_16x16x32_bf16(a2f[kc], bf, Oc[nt], 0, 0, 0);
            }
            __syncthreads();
            cur ^= 1;
        }
    }
    for (int nt = 0; nt < 16; nt++) {
        int dd = nt * 16 + ln;
        float bb = b2[dd];
        #pragma unroll
        for (int rg = 0; rg < 4; rg++) {
            long idx = (long)(R0 + qd * 4 + rg) * 256 + dd;
            out[idx] = out[idx] + Oc[nt][rg] + bb;
        }
    }
}

extern "C" void kernel_launch(void* const* d_in, const int* in_sizes, int n_in,
                              void* d_out, int out_size, void* d_ws, size_t ws_size,
                              hipStream_t stream) {
    const float* x    = (const float*)d_in[0];
    const float* wqkv = (const float*)d_in[1];
    const float* g1   = (const float*)d_in[2];
    const float* be1  = (const float*)d_in[3];
    const float* g2   = (const float*)d_in[4];
    const float* be2  = (const float*)d_in[5];
    const float* w1   = (const float*)d_in[6];
    const float* b1   = (const float*)d_in[7];
    const float* w2   = (const float*)d_in[8];
    const float* b2   = (const float*)d_in[9];
    float* out = (float*)d_out;
    char* ws = (char*)d_ws;
    short* WQKV  = (short*)(ws);
    short* W1B   = (short*)(ws + (512l << 10));
    short* W2B   = (short*)(ws + (1l << 20));
    short* XN    = (short*)(ws + (2l << 20));
    short* Qb    = (short*)(ws + (18l << 20));
    short* Kb    = (short*)(ws + (34l << 20));
    short* VTb   = (short*)(ws + (50l << 20));
    float* Opart = (float*)(ws + (66l << 20));
    float* lpart = (float*)(ws + (130l << 20));

    k_cvt<<<1024, 256, 0, stream>>>(wqkv, w1, w2, WQKV, W1B, W2B);
    k_ln<<<8192, 256, 0, stream>>>(x, g1, be1, XN);
    k_qkv<<<dim3(12, 512), 256, 0, stream>>>(XN, WQKV, Qb, Kb, VTb);
    k_attn<<<dim3(32, 8), 256, 0, stream>>>(Qb, Kb, VTb, Opart, lpart);
    k_merge<<<8192, 256, 0, stream>>>(x, Opart, lpart, out);
    k_ln<<<8192, 256, 0, stream>>>(out, g2, be2, XN);
    k_mlp<<<512, 256, 0, stream>>>(XN, W1B, W2B, b1, b2, out);
}

// Round 6
// 487.680 us; speedup vs baseline: 2.0107x; 2.0107x over previous
//
#include <hip/hip_runtime.h>

// AttentionBlock — x(8,1024,4,256) fp32, full 4096x4096 attention per batch
// (heads merged), qkv interleaved (e = 3*dd + which), MLP 256->1024->256.
// R6: k_attn = R4 structure (BM=128, 4 waves, 1 blk/CU, 64KB LDS, 1 barrier)
//  + V staged via global_load_lds with 16B-granule source swizzle (R5-proven:
//    conflicts 2.1e7 -> 8.4e6)  + dual-accumulator S^T chains (halve exposed
//    MFMA dep latency at 1 wave/SIMD). No split-K (regs cap occupancy anyway).
// ws layout (66 MB):
//   0        : w_qkv bf16 de-interleaved [Wq|Wk|Wv] (scale folded into Wq)
//   512K     : w1 bf16 (1024x256)
//   1M       : w2 bf16 (256x1024)
//   2M..18M  : XN bf16 (32768x256)
//   18M..34M : Q bf16 [b][i][d]  (pre-scaled by 0.0625*log2e via Wq)
//   34M..50M : K bf16 [b][i][d]
//   50M..66M : V^T bf16 [b][d][i]

typedef __attribute__((ext_vector_type(8))) short bf16x8;
typedef __attribute__((ext_vector_type(4))) short bf16x4;
typedef __attribute__((ext_vector_type(4))) float f32x4;
typedef __attribute__((ext_vector_type(16))) float f32x16;

static __device__ __forceinline__ short f2bf(float f) {
    union { float f; unsigned u; } v; v.f = f;
    unsigned r = (v.u + 0x7FFFu + ((v.u >> 16) & 1u)) >> 16;
    return (short)r;
}

static __device__ __forceinline__ void gll16(const void* g, void* l) {
    __builtin_amdgcn_global_load_lds(
        (const __attribute__((address_space(1))) unsigned*)g,
        (__attribute__((address_space(3))) unsigned*)l, 16, 0, 0);
}

// ---------------- weights fp32 -> bf16, de-interleave w_qkv ----------------
__global__ __launch_bounds__(256) void k_cvt(const float* __restrict__ wqkv,
                                             const float* __restrict__ w1,
                                             const float* __restrict__ w2,
                                             short* __restrict__ owqkv,
                                             short* __restrict__ ow1,
                                             short* __restrict__ ow2) {
    int i = blockIdx.x * 256 + threadIdx.x;
    if (i < 196608) {
        int e = i >> 8, col = i & 255;
        int dd = e / 3, which = e - dd * 3;
        float v = wqkv[i];
        if (which == 0) v *= 0.0625f * 1.44269504f;   // fold scale*log2e into Wq
        owqkv[((which << 8) + dd) * 256 + col] = f2bf(v);
    }
    if (i < 262144) { ow1[i] = f2bf(w1[i]); ow2[i] = f2bf(w2[i]); }
}

// ---------------- layernorm: one wave per row of 256 ----------------
__global__ __launch_bounds__(256) void k_ln(const float* __restrict__ x,
                                            const float* __restrict__ g,
                                            const float* __restrict__ bta,
                                            short* __restrict__ out) {
    int w = threadIdx.x >> 6, lane = threadIdx.x & 63;
    long row = (long)blockIdx.x * 4 + w;
    float4 v = *((const float4*)(x + row * 256) + lane);
    float s = v.x + v.y + v.z + v.w;
    float q = v.x * v.x + v.y * v.y + v.z * v.z + v.w * v.w;
    for (int off = 1; off < 64; off <<= 1) {
        s += __shfl_xor(s, off);
        q += __shfl_xor(q, off);
    }
    float mean = s * (1.0f / 256.0f);
    float var = q * (1.0f / 256.0f) - mean * mean;
    float rstd = rsqrtf(var + 1e-5f);
    float4 gg = *((const float4*)g + lane);
    float4 bb = *((const float4*)bta + lane);
    short4 o;
    o.x = f2bf((v.x - mean) * rstd * gg.x + bb.x);
    o.y = f2bf((v.y - mean) * rstd * gg.y + bb.y);
    o.z = f2bf((v.z - mean) * rstd * gg.z + bb.z);
    o.w = f2bf((v.w - mean) * rstd * gg.w + bb.w);
    *((short4*)(out + row * 256) + lane) = o;
}

// ---------------- QKV projection GEMM + split scatter ----------------
__global__ __launch_bounds__(256) void k_qkv(const short* __restrict__ xn,
                                             const short* __restrict__ wb,
                                             short* __restrict__ Q,
                                             short* __restrict__ K,
                                             short* __restrict__ VT) {
    __shared__ __attribute__((aligned(16))) short lds_a[64 * 264];
    __shared__ __attribute__((aligned(16))) short lds_b[64 * 264];
    int t = threadIdx.x;
    int m0 = blockIdx.y * 64, n0 = blockIdx.x * 64;
    const int4* ga = (const int4*)xn;
    const int4* gb = (const int4*)wb;
    int4* la = (int4*)lds_a;
    int4* lb = (int4*)lds_b;
    for (int it = 0; it < 8; it++) {
        int c = t + 256 * it;
        int r = c >> 5, k = c & 31;
        la[r * 33 + k] = ga[(long)(m0 + r) * 32 + k];
        lb[r * 33 + k] = gb[(n0 + r) * 32 + k];
    }
    __syncthreads();
    int w = t >> 6, lane = t & 63, ln = lane & 15, qd = lane >> 4;
    int moff = (w >> 1) * 32, noff = (w & 1) * 32;
    f32x4 acc[2][2] = {};
    for (int ks = 0; ks < 8; ks++) {
        bf16x8 a0 = *(const bf16x8*)&lds_a[(moff + ln) * 264 + ks * 32 + qd * 8];
        bf16x8 a1 = *(const bf16x8*)&lds_a[(moff + 16 + ln) * 264 + ks * 32 + qd * 8];
        bf16x8 b0 = *(const bf16x8*)&lds_b[(noff + ln) * 264 + ks * 32 + qd * 8];
        bf16x8 b1 = *(const bf16x8*)&lds_b[(noff + 16 + ln) * 264 + ks * 32 + qd * 8];
        acc[0][0] = __builtin_amdgcn_mfma_f32_16x16x32_bf16(a0, b0, acc[0][0], 0, 0, 0);
        acc[0][1] = __builtin_amdgcn_mfma_f32_16x16x32_bf16(a0, b1, acc[0][1], 0, 0, 0);
        acc[1][0] = __builtin_amdgcn_mfma_f32_16x16x32_bf16(a1, b0, acc[1][0], 0, 0, 0);
        acc[1][1] = __builtin_amdgcn_mfma_f32_16x16x32_bf16(a1, b1, acc[1][1], 0, 0, 0);
    }
    for (int mi = 0; mi < 2; mi++)
        for (int nj = 0; nj < 2; nj++)
            for (int rg = 0; rg < 4; rg++) {
                float v = acc[mi][nj][rg];
                int gr = m0 + moff + mi * 16 + qd * 4 + rg;
                int e = n0 + noff + nj * 16 + ln;
                int which = e >> 8, dd = e & 255;
                short bv = f2bf(v);
                if (which == 0) Q[(long)gr * 256 + dd] = bv;
                else if (which == 1) K[(long)gr * 256 + dd] = bv;
                else {
                    int b = gr >> 12, i = gr & 4095;
                    VT[((long)b * 256 + dd) * 4096 + i] = bv;
                }
            }
}

// ---------------- flash attention v6 ----------------
// 4 waves x 32 q = BM 128, BN 32, grid (32,8) = 256 blocks = 1/CU. LDS 64 KB.
// K and V both DMA-staged (source-swizzled), 1 barrier/iter, dual S^T chains.
__global__ __launch_bounds__(256, 1) void k_attn(const short* __restrict__ Q,
                                                 const short* __restrict__ K,
                                                 const short* __restrict__ VT,
                                                 const float* __restrict__ x,
                                                 float* __restrict__ out) {
    __shared__ __attribute__((aligned(16))) short lds_k[2][32 * 256];  // 16 KB x2
    __shared__ __attribute__((aligned(16))) short lds_v[2][256 * 32];  // 16 KB x2
    int t = threadIdx.x, w = t >> 6, l = t & 63, l5 = l & 31, h = l >> 5;
    int b = blockIdx.y;
    int q0 = blockIdx.x * 128 + w * 32;

    // Q fragments: B-operand of 32x32x16 (n=q=lane&31, k=(lane>>5)*8+j)
    bf16x8 qf[16];
    {
        const short* qrow = Q + ((long)(b * 4096 + q0 + l5)) * 256;
        #pragma unroll
        for (int kc = 0; kc < 16; kc++) qf[kc] = *(const bf16x8*)(qrow + kc * 16 + h * 8);
    }
    f32x16 O[8] = {};
    float lsum = 0.f;

    const char* Kb = (const char*)(K + (long)b * 4096 * 256);
    const char* Vb = (const char*)(VT + (long)b * 256 * 4096);

    // K DMA: wave w stages rows w*8..w*8+7. Lane (h,l5) of instr i -> row
    // r = w*8+i*2+h, LDS slot l5 holds source 16B chunk (l5 ^ r).
    int koff[4];
    #pragma unroll
    for (int i = 0; i < 4; i++) {
        int r = w * 8 + i * 2 + h;
        koff[i] = r * 512 + ((l5 ^ r) * 16);
    }
    // V DMA: linear 16B slot s = w*256 + i*64 + l; row d = s>>2; slot-in-row
    // M = s&3 holds source chunk m = M ^ ((d>>1)&3). Read at (k4^xl)*16+h*8.
    int voff[4];
    #pragma unroll
    for (int i = 0; i < 4; i++) {
        int s = w * 256 + i * 64 + l;
        int d = s >> 2;
        int m = (s & 3) ^ ((d >> 1) & 3);
        voff[i] = d * 8192 + m * 16;
    }
    int xl = (l5 >> 1) & 3;   // V read swizzle term (dt*16 ≡ 0 mod 4)

    // stage tile 0
    #pragma unroll
    for (int i = 0; i < 4; i++)
        gll16(Kb + koff[i], (char*)lds_k[0] + (w * 8 + i * 2) * 512);
    #pragma unroll
    for (int i = 0; i < 4; i++)
        gll16(Vb + voff[i], (char*)lds_v[0] + (w * 256 + i * 64) * 16);
    __syncthreads();

    for (int jt = 0; jt < 128; jt++) {
        int cur = jt & 1;
        if (jt < 127) {
            long ka = (long)(jt + 1) * 16384;    // 32 K-rows * 512 B
            long va = (long)(jt + 1) * 64;       // 32 keys * 2 B per VT row
            #pragma unroll
            for (int i = 0; i < 4; i++)
                gll16(Kb + ka + koff[i], (char*)lds_k[cur ^ 1] + (w * 8 + i * 2) * 512);
            #pragma unroll
            for (int i = 0; i < 4; i++)
                gll16(Vb + va + voff[i], (char*)lds_v[cur ^ 1] + (w * 256 + i * 64) * 16);
        }
        const short* lk = lds_k[cur];
        const char* lv = (const char*)lds_v[cur];
        // S^T[key][q] = sum_d K[key][d]*Q[q][d] — two independent MFMA chains
        f32x16 sta = {}, stb = {};
        #pragma unroll
        for (int kc = 0; kc < 16; kc += 2) {
            int c0 = kc * 2 + h, c1 = (kc + 1) * 2 + h;
            bf16x8 a0 = *(const bf16x8*)(lk + (l5 * 32 + (c0 ^ l5)) * 8);
            bf16x8 a1 = *(const bf16x8*)(lk + (l5 * 32 + (c1 ^ l5)) * 8);
            sta = __builtin_amdgcn_mfma_f32_32x32x16_bf16(a0, qf[kc], sta, 0, 0, 0);
            stb = __builtin_amdgcn_mfma_f32_32x32x16_bf16(a1, qf[kc + 1], stb, 0, 0, 0);
        }
        f32x16 st = sta + stb;
        // P = exp2(S^T); reg quad r4 == B-frag (k chunk) of 32x32x8
        bf16x4 pf[4];
        #pragma unroll
        for (int r4 = 0; r4 < 4; r4++) {
            float p0 = __builtin_amdgcn_exp2f(st[r4 * 4 + 0]);
            float p1 = __builtin_amdgcn_exp2f(st[r4 * 4 + 1]);
            float p2 = __builtin_amdgcn_exp2f(st[r4 * 4 + 2]);
            float p3 = __builtin_amdgcn_exp2f(st[r4 * 4 + 3]);
            lsum += (p0 + p1) + (p2 + p3);
            union { float f; unsigned u; } u0, u1, u2, u3;
            u0.f = p0; u1.f = p1; u2.f = p2; u3.f = p3;
            union { unsigned u[2]; bf16x4 v; } pk;
            pk.u[0] = __builtin_amdgcn_perm(u1.u + 0x8000u, u0.u + 0x8000u, 0x07060302u);
            pk.u[1] = __builtin_amdgcn_perm(u3.u + 0x8000u, u2.u + 0x8000u, 0x07060302u);
            pf[r4] = pk.v;
        }
        // O^T[d][q] += V^T[d][key] P^T[key][q]
        #pragma unroll
        for (int dt = 0; dt < 8; dt++) {
            int d = dt * 32 + l5;
            const char* vrow = lv + d * 64;
            #pragma unroll
            for (int k4 = 0; k4 < 4; k4++) {
                bf16x4 va = *(const bf16x4*)(vrow + ((k4 ^ xl) * 16 + h * 8));
                O[dt] = __builtin_amdgcn_mfma_f32_32x32x8bf16_1k(va, pf[k4], O[dt], 0, 0, 0);
            }
        }
        __syncthreads();
    }

    // epilogue: l reduce, transpose O^T->O via per-wave LDS scratch, out = x+O/l
    float lt = lsum + __shfl_xor(lsum, 32);
    float rinv = 1.0f / lt;
    float* fscr = (float*)lds_k[0] + w * (32 * 33);   // 4224 B per wave
    #pragma unroll
    for (int dt = 0; dt < 8; dt++) {
        #pragma unroll
        for (int r = 0; r < 16; r++) {
            int drow = (r & 3) + 8 * (r >> 2) + 4 * h;
            fscr[drow * 33 + l5] = O[dt][r] * rinv;
        }
        asm volatile("s_waitcnt lgkmcnt(0)" ::: "memory");
        #pragma unroll
        for (int it = 0; it < 16; it++) {
            int ql = it * 2 + h;
            float v = fscr[l5 * 33 + ql];
            long idx = ((long)(b * 4096 + q0 + ql)) * 256 + dt * 32 + l5;
            out[idx] = x[idx] + v;
        }
        asm volatile("s_waitcnt lgkmcnt(0)" ::: "memory");
    }
}

// ---------------- fused MLP: out += silu(xn W1^T + b1) W2^T + b2 ------------
__global__ __launch_bounds__(256) void k_mlp(const short* __restrict__ xn,
                                             const short* __restrict__ w1b,
                                             const short* __restrict__ w2b,
                                             const float* __restrict__ b1,
                                             const float* __restrict__ b2,
                                             float* __restrict__ out) {
    __shared__ __attribute__((aligned(16))) short lds_w[2][16 * 256];  // 8 KB x2
    __shared__ __attribute__((aligned(16))) short lds_h[4][16 * 264];
    int t = threadIdx.x, w = t >> 6, l = t & 63, ln = l & 15, qd = l >> 4;
    int R0 = blockIdx.x * 64 + w * 16;
    short* lhs = lds_h[w];

    bf16x8 a1f[8];
    #pragma unroll
    for (int kc = 0; kc < 8; kc++)
        a1f[kc] = *(const bf16x8*)(xn + (long)(R0 + ln) * 256 + kc * 32 + qd * 8);

    long s1off[2], s2off[2]; int wlds[2];
    #pragma unroll
    for (int i = 0; i < 2; i++) {
        int r = w * 4 + i * 2 + (l >> 5);
        int ch = (l & 31) ^ r;
        s1off[i] = (long)r * 512 + ch * 16;
        s2off[i] = (long)r * 2048 + ch * 16;
        wlds[i] = (w * 4 + i * 2) * 512;
    }
    const char* W1c = (const char*)w1b;
    const char* W2c = (const char*)w2b;

    f32x4 Oc[16] = {};
    #pragma unroll
    for (int i = 0; i < 2; i++)
        gll16(W1c + s1off[i], (char*)lds_w[0] + wlds[i]);
    __syncthreads();
    int cur = 0;

    for (int pass = 0; pass < 4; pass++) {
        for (int nt = 0; nt < 16; nt++) {
            if (nt < 15) {
                long base = (long)(pass * 256 + (nt + 1) * 16) * 512;
                #pragma unroll
                for (int i = 0; i < 2; i++)
                    gll16(W1c + base + s1off[i], (char*)lds_w[cur ^ 1] + wlds[i]);
            } else {
                long base = (long)pass * 512;
                #pragma unroll
                for (int i = 0; i < 2; i++)
                    gll16(W2c + base + s2off[i], (char*)lds_w[cur ^ 1] + wlds[i]);
            }
            f32x4 acc = {};
            const short* lw = lds_w[cur];
            #pragma unroll
            for (int kc = 0; kc < 8; kc++) {
                int cc = kc * 4 + qd;
                bf16x8 bf = *(const bf16x8*)(lw + (ln * 32 + (cc ^ ln)) * 8);
                acc = __builtin_amdgcn_mfma_f32_16x16x32_bf16(a1f[kc], bf, acc, 0, 0, 0);
            }
            float bb = b1[pass * 256 + nt * 16 + ln];
            #pragma unroll
            for (int rg = 0; rg < 4; rg++) {
                float z = acc[rg] + bb;
                float sv = z / (1.0f + __expf(-z));
                lhs[(qd * 4 + rg) * 264 + nt * 16 + ln] = f2bf(sv);
            }
            __syncthreads();
            cur ^= 1;
        }
        bf16x8 a2f[8];
        #pragma unroll
        for (int kc = 0; kc < 8; kc++)
            a2f[kc] = *(const bf16x8*)&lhs[ln * 264 + kc * 32 + qd * 8];
        for (int nt = 0; nt < 16; nt++) {
            if (nt < 15) {
                long base = (long)((nt + 1) * 16) * 2048 + (long)pass * 512;
                #pragma unroll
                for (int i = 0; i < 2; i++)
                    gll16(W2c + base + s2off[i], (char*)lds_w[cur ^ 1] + wlds[i]);
            } else if (pass < 3) {
                long base = (long)((pass + 1) * 256) * 512;
                #pragma unroll
                for (int i = 0; i < 2; i++)
                    gll16(W1c + base + s1off[i], (char*)lds_w[cur ^ 1] + wlds[i]);
            }
            const short* lw = lds_w[cur];
            #pragma unroll
            for (int kc = 0; kc < 8; kc++) {
                int cc = kc * 4 + qd;
                bf16x8 bf = *(const bf16x8*)(lw + (ln * 32 + (cc ^ ln)) * 8);
                Oc[nt] = __builtin_amdgcn_mfma_f32_16x16x32_bf16(a2f[kc], bf, Oc[nt], 0, 0, 0);
            }
            __syncthreads();
            cur ^= 1;
        }
    }
    for (int nt = 0; nt < 16; nt++) {
        int dd = nt * 16 + ln;
        float bb = b2[dd];
        #pragma unroll
        for (int rg = 0; rg < 4; rg++) {
            long idx = (long)(R0 + qd * 4 + rg) * 256 + dd;
            out[idx] = out[idx] + Oc[nt][rg] + bb;
        }
    }
}

extern "C" void kernel_launch(void* const* d_in, const int* in_sizes, int n_in,
                              void* d_out, int out_size, void* d_ws, size_t ws_size,
                              hipStream_t stream) {
    const float* x    = (const float*)d_in[0];
    const float* wqkv = (const float*)d_in[1];
    const float* g1   = (const float*)d_in[2];
    const float* be1  = (const float*)d_in[3];
    const float* g2   = (const float*)d_in[4];
    const float* be2  = (const float*)d_in[5];
    const float* w1   = (const float*)d_in[6];
    const float* b1   = (const float*)d_in[7];
    const float* w2   = (const float*)d_in[8];
    const float* b2   = (const float*)d_in[9];
    float* out = (float*)d_out;
    char* ws = (char*)d_ws;
    short* WQKV = (short*)(ws);
    short* W1B  = (short*)(ws + (512l << 10));
    short* W2B  = (short*)(ws + (1l << 20));
    short* XN   = (short*)(ws + (2l << 20));
    short* Qb   = (short*)(ws + (18l << 20));
    short* Kb   = (short*)(ws + (34l << 20));
    short* VTb  = (short*)(ws + (50l << 20));

    k_cvt<<<1024, 256, 0, stream>>>(wqkv, w1, w2, WQKV, W1B, W2B);
    k_ln<<<8192, 256, 0, stream>>>(x, g1, be1, XN);
    k_qkv<<<dim3(12, 512), 256, 0, stream>>>(XN, WQKV, Qb, Kb, VTb);
    k_attn<<<dim3(32, 8), 256, 0, stream>>>(Qb, Kb, VTb, x, out);
    k_ln<<<8192, 256, 0, stream>>>(out, g2, be2, XN);
    k_mlp<<<512, 256, 0, stream>>>(XN, W1B, W2B, b1, b2, out);
}

// Round 7
// 478.708 us; speedup vs baseline: 2.0484x; 1.0187x over previous
//
#include <hip/hip_runtime.h>

// AttentionBlock — x(8,1024,4,256) fp32, full 4096x4096 attention per batch
// (heads merged), qkv interleaved (e = 3*dd + which), MLP 256->1024->256.
// R7: k_attn = R6 loop body (160 VGPR, no spill) + split-K x2 over keys
// (exact merge under no-max softmax): grid 512 -> 2 blocks/CU -> 2 waves/SIMD
// so one block's compute overlaps the other's barrier drain. k_merge combines.
// ws layout (131 MB):
//   0        : w_qkv bf16 de-interleaved [Wq|Wk|Wv] (scale folded into Wq)
//   512K     : w1 bf16 (1024x256)
//   1M       : w2 bf16 (256x1024)
//   2M..18M  : XN bf16 (32768x256)
//   18M..34M : Q bf16 [b][i][d]  (pre-scaled by 0.0625*log2e via Wq)
//   34M..50M : K bf16 [b][i][d]
//   50M..66M : V^T bf16 [b][d][i]
//   66M..130M: Opart fp32 [sp][b][q][d]
//   130M+    : lpart fp32 [sp][b*4096+q]

typedef __attribute__((ext_vector_type(8))) short bf16x8;
typedef __attribute__((ext_vector_type(4))) short bf16x4;
typedef __attribute__((ext_vector_type(4))) float f32x4;
typedef __attribute__((ext_vector_type(16))) float f32x16;

static __device__ __forceinline__ short f2bf(float f) {
    union { float f; unsigned u; } v; v.f = f;
    unsigned r = (v.u + 0x7FFFu + ((v.u >> 16) & 1u)) >> 16;
    return (short)r;
}

static __device__ __forceinline__ void gll16(const void* g, void* l) {
    __builtin_amdgcn_global_load_lds(
        (const __attribute__((address_space(1))) unsigned*)g,
        (__attribute__((address_space(3))) unsigned*)l, 16, 0, 0);
}

// ---------------- weights fp32 -> bf16, de-interleave w_qkv ----------------
__global__ __launch_bounds__(256) void k_cvt(const float* __restrict__ wqkv,
                                             const float* __restrict__ w1,
                                             const float* __restrict__ w2,
                                             short* __restrict__ owqkv,
                                             short* __restrict__ ow1,
                                             short* __restrict__ ow2) {
    int i = blockIdx.x * 256 + threadIdx.x;
    if (i < 196608) {
        int e = i >> 8, col = i & 255;
        int dd = e / 3, which = e - dd * 3;
        float v = wqkv[i];
        if (which == 0) v *= 0.0625f * 1.44269504f;   // fold scale*log2e into Wq
        owqkv[((which << 8) + dd) * 256 + col] = f2bf(v);
    }
    if (i < 262144) { ow1[i] = f2bf(w1[i]); ow2[i] = f2bf(w2[i]); }
}

// ---------------- layernorm: one wave per row of 256 ----------------
__global__ __launch_bounds__(256) void k_ln(const float* __restrict__ x,
                                            const float* __restrict__ g,
                                            const float* __restrict__ bta,
                                            short* __restrict__ out) {
    int w = threadIdx.x >> 6, lane = threadIdx.x & 63;
    long row = (long)blockIdx.x * 4 + w;
    float4 v = *((const float4*)(x + row * 256) + lane);
    float s = v.x + v.y + v.z + v.w;
    float q = v.x * v.x + v.y * v.y + v.z * v.z + v.w * v.w;
    for (int off = 1; off < 64; off <<= 1) {
        s += __shfl_xor(s, off);
        q += __shfl_xor(q, off);
    }
    float mean = s * (1.0f / 256.0f);
    float var = q * (1.0f / 256.0f) - mean * mean;
    float rstd = rsqrtf(var + 1e-5f);
    float4 gg = *((const float4*)g + lane);
    float4 bb = *((const float4*)bta + lane);
    short4 o;
    o.x = f2bf((v.x - mean) * rstd * gg.x + bb.x);
    o.y = f2bf((v.y - mean) * rstd * gg.y + bb.y);
    o.z = f2bf((v.z - mean) * rstd * gg.z + bb.z);
    o.w = f2bf((v.w - mean) * rstd * gg.w + bb.w);
    *((short4*)(out + row * 256) + lane) = o;
}

// ---------------- QKV projection GEMM + split scatter ----------------
__global__ __launch_bounds__(256) void k_qkv(const short* __restrict__ xn,
                                             const short* __restrict__ wb,
                                             short* __restrict__ Q,
                                             short* __restrict__ K,
                                             short* __restrict__ VT) {
    __shared__ __attribute__((aligned(16))) short lds_a[64 * 264];
    __shared__ __attribute__((aligned(16))) short lds_b[64 * 264];
    int t = threadIdx.x;
    int m0 = blockIdx.y * 64, n0 = blockIdx.x * 64;
    const int4* ga = (const int4*)xn;
    const int4* gb = (const int4*)wb;
    int4* la = (int4*)lds_a;
    int4* lb = (int4*)lds_b;
    for (int it = 0; it < 8; it++) {
        int c = t + 256 * it;
        int r = c >> 5, k = c & 31;
        la[r * 33 + k] = ga[(long)(m0 + r) * 32 + k];
        lb[r * 33 + k] = gb[(n0 + r) * 32 + k];
    }
    __syncthreads();
    int w = t >> 6, lane = t & 63, ln = lane & 15, qd = lane >> 4;
    int moff = (w >> 1) * 32, noff = (w & 1) * 32;
    f32x4 acc[2][2] = {};
    for (int ks = 0; ks < 8; ks++) {
        bf16x8 a0 = *(const bf16x8*)&lds_a[(moff + ln) * 264 + ks * 32 + qd * 8];
        bf16x8 a1 = *(const bf16x8*)&lds_a[(moff + 16 + ln) * 264 + ks * 32 + qd * 8];
        bf16x8 b0 = *(const bf16x8*)&lds_b[(noff + ln) * 264 + ks * 32 + qd * 8];
        bf16x8 b1 = *(const bf16x8*)&lds_b[(noff + 16 + ln) * 264 + ks * 32 + qd * 8];
        acc[0][0] = __builtin_amdgcn_mfma_f32_16x16x32_bf16(a0, b0, acc[0][0], 0, 0, 0);
        acc[0][1] = __builtin_amdgcn_mfma_f32_16x16x32_bf16(a0, b1, acc[0][1], 0, 0, 0);
        acc[1][0] = __builtin_amdgcn_mfma_f32_16x16x32_bf16(a1, b0, acc[1][0], 0, 0, 0);
        acc[1][1] = __builtin_amdgcn_mfma_f32_16x16x32_bf16(a1, b1, acc[1][1], 0, 0, 0);
    }
    for (int mi = 0; mi < 2; mi++)
        for (int nj = 0; nj < 2; nj++)
            for (int rg = 0; rg < 4; rg++) {
                float v = acc[mi][nj][rg];
                int gr = m0 + moff + mi * 16 + qd * 4 + rg;
                int e = n0 + noff + nj * 16 + ln;
                int which = e >> 8, dd = e & 255;
                short bv = f2bf(v);
                if (which == 0) Q[(long)gr * 256 + dd] = bv;
                else if (which == 1) K[(long)gr * 256 + dd] = bv;
                else {
                    int b = gr >> 12, i = gr & 4095;
                    VT[((long)b * 256 + dd) * 4096 + i] = bv;
                }
            }
}

// ---------------- flash attention v7 (split-K x2) ----------------
// grid (64, 8): x = qt*2 + sp. 4 waves x 32 q = BM 128; each block covers
// keys [sp*2048, sp*2048+2048) in 64 iters of BN=32. 2 blocks/CU.
__global__ __launch_bounds__(256, 2) void k_attn(const short* __restrict__ Q,
                                                 const short* __restrict__ K,
                                                 const short* __restrict__ VT,
                                                 float* __restrict__ Opart,
                                                 float* __restrict__ lpart) {
    __shared__ __attribute__((aligned(16))) short lds_k[2][32 * 256];  // 16 KB x2
    __shared__ __attribute__((aligned(16))) short lds_v[2][256 * 32];  // 16 KB x2
    int t = threadIdx.x, w = t >> 6, l = t & 63, l5 = l & 31, h = l >> 5;
    int qt = blockIdx.x >> 1, sp = blockIdx.x & 1;
    int b = blockIdx.y;
    int q0 = qt * 128 + w * 32;

    // Q fragments: B-operand of 32x32x16 (n=q=lane&31, k=(lane>>5)*8+j)
    bf16x8 qf[16];
    {
        const short* qrow = Q + ((long)(b * 4096 + q0 + l5)) * 256;
        #pragma unroll
        for (int kc = 0; kc < 16; kc++) qf[kc] = *(const bf16x8*)(qrow + kc * 16 + h * 8);
    }
    f32x16 O[8] = {};
    float lsum = 0.f;

    const char* Kb = (const char*)K + ((long)(b * 4096 + sp * 2048)) * 512;
    const char* Vb = (const char*)VT + (long)b * 256 * 8192 + (long)sp * 4096;

    // K DMA: wave w stages rows w*8..w*8+7. Lane (h,l5) of instr i -> row
    // r = w*8+i*2+h, LDS slot l5 holds source 16B chunk (l5 ^ r).
    int koff[4];
    #pragma unroll
    for (int i = 0; i < 4; i++) {
        int r = w * 8 + i * 2 + h;
        koff[i] = r * 512 + ((l5 ^ r) * 16);
    }
    // V DMA: linear 16B slot s = w*256 + i*64 + l; row d = s>>2; slot-in-row
    // M = s&3 holds source chunk m = M ^ ((d>>1)&3). Read at (k4^xl)*16+h*8.
    int voff[4];
    #pragma unroll
    for (int i = 0; i < 4; i++) {
        int s = w * 256 + i * 64 + l;
        int d = s >> 2;
        int m = (s & 3) ^ ((d >> 1) & 3);
        voff[i] = d * 8192 + m * 16;
    }
    int xl = (l5 >> 1) & 3;   // V read swizzle term (dt*16 ≡ 0 mod 4)

    // stage tile 0
    #pragma unroll
    for (int i = 0; i < 4; i++)
        gll16(Kb + koff[i], (char*)lds_k[0] + (w * 8 + i * 2) * 512);
    #pragma unroll
    for (int i = 0; i < 4; i++)
        gll16(Vb + voff[i], (char*)lds_v[0] + (w * 256 + i * 64) * 16);
    __syncthreads();

    for (int jt = 0; jt < 64; jt++) {
        int cur = jt & 1;
        if (jt < 63) {
            long ka = (long)(jt + 1) * 16384;    // 32 K-rows * 512 B
            long va = (long)(jt + 1) * 64;       // 32 keys * 2 B per VT row
            #pragma unroll
            for (int i = 0; i < 4; i++)
                gll16(Kb + ka + koff[i], (char*)lds_k[cur ^ 1] + (w * 8 + i * 2) * 512);
            #pragma unroll
            for (int i = 0; i < 4; i++)
                gll16(Vb + va + voff[i], (char*)lds_v[cur ^ 1] + (w * 256 + i * 64) * 16);
        }
        const short* lk = lds_k[cur];
        const char* lv = (const char*)lds_v[cur];
        // S^T[key][q] = sum_d K[key][d]*Q[q][d] — two independent MFMA chains
        f32x16 sta = {}, stb = {};
        #pragma unroll
        for (int kc = 0; kc < 16; kc += 2) {
            int c0 = kc * 2 + h, c1 = (kc + 1) * 2 + h;
            bf16x8 a0 = *(const bf16x8*)(lk + (l5 * 32 + (c0 ^ l5)) * 8);
            bf16x8 a1 = *(const bf16x8*)(lk + (l5 * 32 + (c1 ^ l5)) * 8);
            sta = __builtin_amdgcn_mfma_f32_32x32x16_bf16(a0, qf[kc], sta, 0, 0, 0);
            stb = __builtin_amdgcn_mfma_f32_32x32x16_bf16(a1, qf[kc + 1], stb, 0, 0, 0);
        }
        f32x16 st = sta + stb;
        // P = exp2(S^T); reg quad r4 == B-frag (k chunk) of 32x32x8
        bf16x4 pf[4];
        #pragma unroll
        for (int r4 = 0; r4 < 4; r4++) {
            float p0 = __builtin_amdgcn_exp2f(st[r4 * 4 + 0]);
            float p1 = __builtin_amdgcn_exp2f(st[r4 * 4 + 1]);
            float p2 = __builtin_amdgcn_exp2f(st[r4 * 4 + 2]);
            float p3 = __builtin_amdgcn_exp2f(st[r4 * 4 + 3]);
            lsum += (p0 + p1) + (p2 + p3);
            union { float f; unsigned u; } u0, u1, u2, u3;
            u0.f = p0; u1.f = p1; u2.f = p2; u3.f = p3;
            union { unsigned u[2]; bf16x4 v; } pk;
            pk.u[0] = __builtin_amdgcn_perm(u1.u + 0x8000u, u0.u + 0x8000u, 0x07060302u);
            pk.u[1] = __builtin_amdgcn_perm(u3.u + 0x8000u, u2.u + 0x8000u, 0x07060302u);
            pf[r4] = pk.v;
        }
        // O^T[d][q] += V^T[d][key] P^T[key][q]
        #pragma unroll
        for (int dt = 0; dt < 8; dt++) {
            int d = dt * 32 + l5;
            const char* vrow = lv + d * 64;
            #pragma unroll
            for (int k4 = 0; k4 < 4; k4++) {
                bf16x4 va = *(const bf16x4*)(vrow + ((k4 ^ xl) * 16 + h * 8));
                O[dt] = __builtin_amdgcn_mfma_f32_32x32x8bf16_1k(va, pf[k4], O[dt], 0, 0, 0);
            }
        }
        __syncthreads();
    }

    // epilogue: write partial l and unnormalized partial O (merge divides)
    long obase = ((long)(sp * 8 + b)) * 4096 * 256;
    long lbase = (long)(sp * 8 + b) * 4096;
    float lt = lsum + __shfl_xor(lsum, 32);
    if (h == 0) lpart[lbase + q0 + l5] = lt;
    float* fscr = (float*)lds_k[0] + w * (32 * 33);   // per-wave scratch
    #pragma unroll
    for (int dt = 0; dt < 8; dt++) {
        #pragma unroll
        for (int r = 0; r < 16; r++) {
            int drow = (r & 3) + 8 * (r >> 2) + 4 * h;
            fscr[drow * 33 + l5] = O[dt][r];
        }
        asm volatile("s_waitcnt lgkmcnt(0)" ::: "memory");
        #pragma unroll
        for (int it = 0; it < 16; it++) {
            int ql = it * 2 + h;
            float v = fscr[l5 * 33 + ql];
            Opart[obase + (long)(q0 + ql) * 256 + dt * 32 + l5] = v;
        }
        asm volatile("s_waitcnt lgkmcnt(0)" ::: "memory");
    }
}

// ---------------- merge: out = x + (Oa+Ob) / (la+lb) ----------------
__global__ __launch_bounds__(256) void k_merge(const float* __restrict__ x,
                                               const float* __restrict__ Op,
                                               const float* __restrict__ lp,
                                               float* __restrict__ out) {
    long i4 = (long)blockIdx.x * 256 + threadIdx.x;   // float4 units
    long i = i4 * 4;
    int row = (int)(i >> 8);
    float li = lp[row] + lp[32768 + row];
    float rinv = 1.0f / li;
    float4 a = *(const float4*)(Op + i);
    float4 bq = *(const float4*)(Op + (long)8 * 4096 * 256 + i);
    float4 xx = *(const float4*)(x + i);
    float4 o;
    o.x = xx.x + (a.x + bq.x) * rinv;
    o.y = xx.y + (a.y + bq.y) * rinv;
    o.z = xx.z + (a.z + bq.z) * rinv;
    o.w = xx.w + (a.w + bq.w) * rinv;
    *(float4*)(out + i) = o;
}

// ---------------- fused MLP: out += silu(xn W1^T + b1) W2^T + b2 ------------
__global__ __launch_bounds__(256) void k_mlp(const short* __restrict__ xn,
                                             const short* __restrict__ w1b,
                                             const short* __restrict__ w2b,
                                             const float* __restrict__ b1,
                                             const float* __restrict__ b2,
                                             float* __restrict__ out) {
    __shared__ __attribute__((aligned(16))) short lds_w[2][16 * 256];  // 8 KB x2
    __shared__ __attribute__((aligned(16))) short lds_h[4][16 * 264];
    int t = threadIdx.x, w = t >> 6, l = t & 63, ln = l & 15, qd = l >> 4;
    int R0 = blockIdx.x * 64 + w * 16;
    short* lhs = lds_h[w];

    bf16x8 a1f[8];
    #pragma unroll
    for (int kc = 0; kc < 8; kc++)
        a1f[kc] = *(const bf16x8*)(xn + (long)(R0 + ln) * 256 + kc * 32 + qd * 8);

    long s1off[2], s2off[2]; int wlds[2];
    #pragma unroll
    for (int i = 0; i < 2; i++) {
        int r = w * 4 + i * 2 + (l >> 5);
        int ch = (l & 31) ^ r;
        s1off[i] = (long)r * 512 + ch * 16;
        s2off[i] = (long)r * 2048 + ch * 16;
        wlds[i] = (w * 4 + i * 2) * 512;
    }
    const char* W1c = (const char*)w1b;
    const char* W2c = (const char*)w2b;

    f32x4 Oc[16] = {};
    #pragma unroll
    for (int i = 0; i < 2; i++)
        gll16(W1c + s1off[i], (char*)lds_w[0] + wlds[i]);
    __syncthreads();
    int cur = 0;

    for (int pass = 0; pass < 4; pass++) {
        for (int nt = 0; nt < 16; nt++) {
            if (nt < 15) {
                long base = (long)(pass * 256 + (nt + 1) * 16) * 512;
                #pragma unroll
                for (int i = 0; i < 2; i++)
                    gll16(W1c + base + s1off[i], (char*)lds_w[cur ^ 1] + wlds[i]);
            } else {
                long base = (long)pass * 512;
                #pragma unroll
                for (int i = 0; i < 2; i++)
                    gll16(W2c + base + s2off[i], (char*)lds_w[cur ^ 1] + wlds[i]);
            }
            f32x4 acc = {};
            const short* lw = lds_w[cur];
            #pragma unroll
            for (int kc = 0; kc < 8; kc++) {
                int cc = kc * 4 + qd;
                bf16x8 bf = *(const bf16x8*)(lw + (ln * 32 + (cc ^ ln)) * 8);
                acc = __builtin_amdgcn_mfma_f32_16x16x32_bf16(a1f[kc], bf, acc, 0, 0, 0);
            }
            float bb = b1[pass * 256 + nt * 16 + ln];
            #pragma unroll
            for (int rg = 0; rg < 4; rg++) {
                float z = acc[rg] + bb;
                float sv = z / (1.0f + __expf(-z));
                lhs[(qd * 4 + rg) * 264 + nt * 16 + ln] = f2bf(sv);
            }
            __syncthreads();
            cur ^= 1;
        }
        bf16x8 a2f[8];
        #pragma unroll
        for (int kc = 0; kc < 8; kc++)
            a2f[kc] = *(const bf16x8*)&lhs[ln * 264 + kc * 32 + qd * 8];
        for (int nt = 0; nt < 16; nt++) {
            if (nt < 15) {
                long base = (long)((nt + 1) * 16) * 2048 + (long)pass * 512;
                #pragma unroll
                for (int i = 0; i < 2; i++)
                    gll16(W2c + base + s2off[i], (char*)lds_w[cur ^ 1] + wlds[i]);
            } else if (pass < 3) {
                long base = (long)((pass + 1) * 256) * 512;
                #pragma unroll
                for (int i = 0; i < 2; i++)
                    gll16(W1c + base + s1off[i], (char*)lds_w[cur ^ 1] + wlds[i]);
            }
            const short* lw = lds_w[cur];
            #pragma unroll
            for (int kc = 0; kc < 8; kc++) {
                int cc = kc * 4 + qd;
                bf16x8 bf = *(const bf16x8*)(lw + (ln * 32 + (cc ^ ln)) * 8);
                Oc[nt] = __builtin_amdgcn_mfma_f32_16x16x32_bf16(a2f[kc], bf, Oc[nt], 0, 0, 0);
            }
            __syncthreads();
            cur ^= 1;
        }
    }
    for (int nt = 0; nt < 16; nt++) {
        int dd = nt * 16 + ln;
        float bb = b2[dd];
        #pragma unroll
        for (int rg = 0; rg < 4; rg++) {
            long idx = (long)(R0 + qd * 4 + rg) * 256 + dd;
            out[idx] = out[idx] + Oc[nt][rg] + bb;
        }
    }
}

extern "C" void kernel_launch(void* const* d_in, const int* in_sizes, int n_in,
                              void* d_out, int out_size, void* d_ws, size_t ws_size,
                              hipStream_t stream) {
    const float* x    = (const float*)d_in[0];
    const float* wqkv = (const float*)d_in[1];
    const float* g1   = (const float*)d_in[2];
    const float* be1  = (const float*)d_in[3];
    const float* g2   = (const float*)d_in[4];
    const float* be2  = (const float*)d_in[5];
    const float* w1   = (const float*)d_in[6];
    const float* b1   = (const float*)d_in[7];
    const float* w2   = (const float*)d_in[8];
    const float* b2   = (const float*)d_in[9];
    float* out = (float*)d_out;
    char* ws = (char*)d_ws;
    short* WQKV  = (short*)(ws);
    short* W1B   = (short*)(ws + (512l << 10));
    short* W2B   = (short*)(ws + (1l << 20));
    short* XN    = (short*)(ws + (2l << 20));
    short* Qb    = (short*)(ws + (18l << 20));
    short* Kb    = (short*)(ws + (34l << 20));
    short* VTb   = (short*)(ws + (50l << 20));
    float* Opart = (float*)(ws + (66l << 20));
    float* lpart = (float*)(ws + (130l << 20));

    k_cvt<<<1024, 256, 0, stream>>>(wqkv, w1, w2, WQKV, W1B, W2B);
    k_ln<<<8192, 256, 0, stream>>>(x, g1, be1, XN);
    k_qkv<<<dim3(12, 512), 256, 0, stream>>>(XN, WQKV, Qb, Kb, VTb);
    k_attn<<<dim3(64, 8), 256, 0, stream>>>(Qb, Kb, VTb, Opart, lpart);
    k_merge<<<8192, 256, 0, stream>>>(x, Opart, lpart, out);
    k_ln<<<8192, 256, 0, stream>>>(out, g2, be2, XN);
    k_mlp<<<512, 256, 0, stream>>>(XN, W1B, W2B, b1, b2, out);
}